// Round 4
// baseline (31.661 us; speedup 1.0000x reference)
//
#include <hip/hip_runtime.h>

// N_TOTAL = 10100, D = 128, B = 2048. F dense-stored, ~33 nnz/row.
// R=4 batch rows per block (512 threads):
//   P1: 128 threads/row scan the F row (float4), compact (idx,w) into LDS
//   P2: 16 groups x 32 lanes; group g fetches entry k's full E row as
//       lane-float4s (one coalesced 512B load per entry) -> reg accumulate,
//       all 4 rows back-to-back with no barriers (deep MLP)
//   P3: fused linear: W read coalesced ONCE per block (8 float4/thread),
//       reused for all 4 rows; 32-lane shuffle reduce per output j
//   out = bias + agg @ W^T, rows stored coalesced.

#define NTOT 10100
#define NV4  2525    // NTOT/4 exact
#define DIM  128
#define CAP  256     // nnz ~ Poisson(32); dense fallback if exceeded
#define TPB  512
#define R    4

__global__ __launch_bounds__(TPB, 4) void friendship_kernel(
    const int*   __restrict__ uids,
    const float* __restrict__ F,
    const float* __restrict__ E,
    const float* __restrict__ W,
    const float* __restrict__ bias,
    float*       __restrict__ out,
    int B)
{
    __shared__ int   s_idx[R][CAP];
    __shared__ float s_w[R][CAP];
    __shared__ int   s_cnt[R];
    __shared__ float s_red[R][16][DIM];   // 32 KB partials
    __shared__ float s_agg[R][DIM];
    __shared__ float s_out[R][DIM];

    const int tid  = threadIdx.x;
    const int base = blockIdx.x * R;

    if (tid < R) s_cnt[tid] = 0;
    __syncthreads();

    // ---- Phase 1: scan + compact, 128 threads per row ----
    const int tr = tid >> 7;       // row 0..3 (wave-uniform: 2 waves/row)
    const int lr = tid & 127;
    const bool row_ok = (base + tr) < B;
    if (row_ok) {
        const int uid = uids[base + tr];
        const float4* Frow4 = (const float4*)(F + (size_t)uid * NTOT); // 16B-aligned
        for (int i = lr; i < NV4; i += 128) {
            float4 v = Frow4[i];
            int n = i * 4;
            bool ba = v.x != 0.0f, bb = v.y != 0.0f, bc = v.z != 0.0f, bd = v.w != 0.0f;
            int  m  = (int)ba + (int)bb + (int)bc + (int)bd;
            if (m) {
                int p = atomicAdd(&s_cnt[tr], m);
                if (p + m <= CAP) {
                    if (ba) { s_idx[tr][p] = n;     s_w[tr][p] = v.x; ++p; }
                    if (bb) { s_idx[tr][p] = n + 1; s_w[tr][p] = v.y; ++p; }
                    if (bc) { s_idx[tr][p] = n + 2; s_w[tr][p] = v.z; ++p; }
                    if (bd) { s_idx[tr][p] = n + 3; s_w[tr][p] = v.w; ++p; }
                }
            }
        }
    }
    __syncthreads();

    // ---- Phase 2: acc[r] (float4 over d=4l..4l+3) = sum_k w_k * E[n_k] ----
    const int g = tid >> 5;   // entry-group 0..15
    const int l = tid & 31;   // lane: owns d = 4l..4l+3
    float4 acc[R];
    #pragma unroll
    for (int r = 0; r < R; ++r) acc[r] = make_float4(0.f, 0.f, 0.f, 0.f);

    #pragma unroll
    for (int r = 0; r < R; ++r) {
        if (base + r >= B) break;
        const int cnt = s_cnt[r];
        if (cnt <= CAP) {
            for (int k = g; k < cnt; k += 16) {
                int   n = s_idx[r][k];
                float w = s_w[r][k];
                float4 ev = *(const float4*)(E + (size_t)n * DIM + l * 4);
                acc[r].x += w * ev.x; acc[r].y += w * ev.y;
                acc[r].z += w * ev.z; acc[r].w += w * ev.w;
            }
        } else {  // impossible-in-practice dense fallback (correctness net)
            const float* Fr = F + (size_t)uids[base + r] * NTOT;
            for (int n = g; n < NTOT; n += 16) {
                float w = Fr[n];
                float4 ev = *(const float4*)(E + (size_t)n * DIM + l * 4);
                acc[r].x += w * ev.x; acc[r].y += w * ev.y;
                acc[r].z += w * ev.z; acc[r].w += w * ev.w;
            }
        }
    }
    #pragma unroll
    for (int r = 0; r < R; ++r)
        *(float4*)&s_red[r][g][l * 4] = acc[r];
    __syncthreads();

    // cross-group reduce: thread (tr, lr) sums 16 partials for d=lr
    {
        float sum = 0.0f;
        #pragma unroll
        for (int gg = 0; gg < 16; ++gg) sum += s_red[tr][gg][lr];
        s_agg[tr][lr] = sum;
    }
    __syncthreads();

    // ---- Phase 3: out[j] = bias[j] + sum_d agg[d]*W[j][d] ----
    // W read coalesced once (8 float4/thread), reused for all 4 rows.
    const float4* W4 = (const float4*)W;
    #pragma unroll
    for (int q = 0; q < 8; ++q) {
        int i4 = tid + TPB * q;          // flat float4 index 0..4095
        float4 wv = W4[i4];              // fully coalesced, L2-hot
        int j  = i4 >> 5;                // output feature owned by this 32-lane group
        int dd = (i4 & 31) * 4;
        #pragma unroll
        for (int r = 0; r < R; ++r) {
            float4 ag = *(const float4*)&s_agg[r][dd];
            float p = wv.x * ag.x + wv.y * ag.y + wv.z * ag.z + wv.w * ag.w;
            p += __shfl_xor(p, 16);
            p += __shfl_xor(p, 8);
            p += __shfl_xor(p, 4);
            p += __shfl_xor(p, 2);
            p += __shfl_xor(p, 1);
            if ((tid & 31) == 0) s_out[r][j] = p;
        }
    }
    __syncthreads();
    if (row_ok)
        out[(size_t)(base + tr) * DIM + lr] = bias[lr] + s_out[tr][lr];
}

extern "C" void kernel_launch(void* const* d_in, const int* in_sizes, int n_in,
                              void* d_out, int out_size, void* d_ws, size_t ws_size,
                              hipStream_t stream) {
    const int*   uids = (const int*)  d_in[0];
    const float* F    = (const float*)d_in[1];
    const float* E    = (const float*)d_in[2];
    const float* W    = (const float*)d_in[3];
    const float* bias = (const float*)d_in[4];
    float*       out  = (float*)d_out;

    const int B = in_sizes[0];  // 2048
    const int grid = (B + R - 1) / R;
    friendship_kernel<<<grid, TPB, 0, stream>>>(uids, F, E, W, bias, out, B);
}